// Round 2
// baseline (697.346 us; speedup 1.0000x reference)
//
#include <hip/hip_runtime.h>
#include <hip/hip_bf16.h>
#include <stdint.h>

// ---------------------------------------------------------------------------
// TDBU caption step. Structure:
//   K1 gemm chain: td = tanh(step@W_td3.T + h2@W_td1.T + tf@W_td2.T); td2=relu(td@W_td.T)
//   GRU1: gi = td2@Wih.T+bih ; gh = h1prev@Whh.T+bhh ; combine -> h1 (out)
//   hb = h1@W_hidd.T
//   attn kernel (bf16 MFMA, per-b block): S=obj[b]@W_feat.T ; score=sum W_att*tanh(S+hb);
//        softmax -> masks (out); attended = sum_p mask*obj
//   lang = tanh(att@W_l1.T + h1@W_l2.T); lang2 = relu(lang@W_l.T)
//   GRU2: combine -> h2 (out)
// All fp32 except attention GEMM (bf16 MFMA, fp32 accumulate).
// ---------------------------------------------------------------------------

typedef __attribute__((ext_vector_type(8))) short short8;
typedef __attribute__((ext_vector_type(4))) float f32x4;

#define DEV static __device__ __forceinline__

DEV float fast_tanh(float x) {
  float ax = fabsf(x);
  float e = __expf(2.0f * ax);          // overflow -> inf -> t=1, no NaN
  float t = 1.0f - 2.0f / (e + 1.0f);
  return x < 0.0f ? -t : t;
}
DEV float fast_sigmoid(float x) { return 1.0f / (1.0f + __expf(-x)); }
DEV unsigned short f2bf(float x) {
  unsigned u = __float_as_uint(x);
  u += 0x7fffu + ((u >> 16) & 1u);      // round-to-nearest-even
  return (unsigned short)(u >> 16);
}
DEV float bf2f(unsigned short s) { return __uint_as_float(((unsigned)s) << 16); }

// ---------------- generic fp32 GEMM-NT: C = A(M,K) @ W(N,K)^T --------------
// flags: bit0 = accumulate into C; (flags>>2): 0=none 1=relu 2=tanh (applied last)
#define GBM 64
#define GBN 64
#define GBK 32
__global__ __launch_bounds__(256) void gemm_nt(
    const float* __restrict__ A, const float* __restrict__ W,
    const float* __restrict__ bias, float* __restrict__ C,
    int M, int N, int K, int flags)
{
  __shared__ float As[GBK][GBM];   // As[k][m]
  __shared__ float Ws[GBK][GBN];   // Ws[k][n]
  const int bm = blockIdx.x * GBM;
  const int bn = blockIdx.y * GBN;
  const int tid = (int)threadIdx.x;
  const int tx = tid & 15, ty = tid >> 4;   // tx -> n quad, ty -> m quad
  const int q = tid & 7, rr = tid >> 3;     // staging: quad-in-row, row

  float acc[4][4] = {};

  for (int k0 = 0; k0 < K; k0 += GBK) {
#pragma unroll
    for (int h = 0; h < 2; ++h) {
      const int m = rr + h * 32;
      const int kk = k0 + q * 4;
      const float* srcA = A + (size_t)(bm + m) * K + kk;
      const float* srcW = W + (size_t)(bn + m) * K + kk;
      float4 va, vw;
      if (kk + 4 <= K) {
        va = *(const float4*)srcA;
        vw = *(const float4*)srcW;
      } else {
        va.x = (kk + 0 < K) ? srcA[0] : 0.f; va.y = (kk + 1 < K) ? srcA[1] : 0.f;
        va.z = (kk + 2 < K) ? srcA[2] : 0.f; va.w = (kk + 3 < K) ? srcA[3] : 0.f;
        vw.x = (kk + 0 < K) ? srcW[0] : 0.f; vw.y = (kk + 1 < K) ? srcW[1] : 0.f;
        vw.z = (kk + 2 < K) ? srcW[2] : 0.f; vw.w = (kk + 3 < K) ? srcW[3] : 0.f;
      }
      As[q*4+0][m] = va.x; As[q*4+1][m] = va.y; As[q*4+2][m] = va.z; As[q*4+3][m] = va.w;
      Ws[q*4+0][m] = vw.x; Ws[q*4+1][m] = vw.y; Ws[q*4+2][m] = vw.z; Ws[q*4+3][m] = vw.w;
    }
    __syncthreads();
#pragma unroll
    for (int k = 0; k < GBK; ++k) {
      const float4 a = *(const float4*)&As[k][ty * 4];
      const float4 w = *(const float4*)&Ws[k][tx * 4];
      const float av[4] = {a.x, a.y, a.z, a.w};
      const float wv[4] = {w.x, w.y, w.z, w.w};
#pragma unroll
      for (int i = 0; i < 4; ++i)
#pragma unroll
        for (int j = 0; j < 4; ++j)
          acc[i][j] = fmaf(av[i], wv[j], acc[i][j]);
    }
    __syncthreads();
  }

  const int act = flags >> 2;
#pragma unroll
  for (int i = 0; i < 4; ++i) {
    const int m = bm + ty * 4 + i;
    float* cp = C + (size_t)m * N + bn + tx * 4;
    float v[4] = {acc[i][0], acc[i][1], acc[i][2], acc[i][3]};
    if (bias) {
      const float4 bb = *(const float4*)&bias[bn + tx * 4];
      v[0] += bb.x; v[1] += bb.y; v[2] += bb.z; v[3] += bb.w;
    }
    if (flags & 1) {
      const float4 o = *(const float4*)cp;
      v[0] += o.x; v[1] += o.y; v[2] += o.z; v[3] += o.w;
    }
    if (act == 1) {
#pragma unroll
      for (int j = 0; j < 4; ++j) v[j] = fmaxf(v[j], 0.0f);
    } else if (act == 2) {
#pragma unroll
      for (int j = 0; j < 4; ++j) v[j] = fast_tanh(v[j]);
    }
    float4 o; o.x = v[0]; o.y = v[1]; o.z = v[2]; o.w = v[3];
    *(float4*)cp = o;
  }
}

// ---------------- GRU elementwise combine ----------------------------------
__global__ __launch_bounds__(256) void gru_combine(
    const float* __restrict__ gi, const float* __restrict__ gh,
    const float* __restrict__ hprev, float* __restrict__ hnew)
{
  const int i = blockIdx.x * 256 + (int)threadIdx.x;   // over B*H = 524288
  const int b = i >> 9, j = i & 511;
  const float* gib = gi + (size_t)b * 1536;
  const float* ghb = gh + (size_t)b * 1536;
  const float r = fast_sigmoid(gib[j] + ghb[j]);
  const float z = fast_sigmoid(gib[j + 512] + ghb[j + 512]);
  const float n = fast_tanh(gib[j + 1024] + r * ghb[j + 1024]);
  hnew[i] = (1.0f - z) * n + z * hprev[i];
}

// ---------------- fp32 -> bf16 convert -------------------------------------
__global__ __launch_bounds__(256) void cvt_bf16(
    const float* __restrict__ in, unsigned short* __restrict__ out, int n)
{
  const int i = blockIdx.x * 256 + (int)threadIdx.x;
  if (i < n) out[i] = f2bf(in[i]);
}

// ---------------- fused attention: per-b block, bf16 MFMA ------------------
// obj (1024,256,128) f32 ; wf = bf16(W_feat) (512,128) ; hb (1024,512) f32 ;
// watt (512) f32 ; masks_out (1024,256) f32 ; attended (1024,128) f32.
// MFMA f32_16x16x32_bf16 layout used:
//   A: row = l&15, k: elems0-3 = (l>>4)*4+j, elems4-7 = 16+(l>>4)*4+(j-4)
//   B: col = l&15, same k split
//   C/D: col = lane&15, row = (lane>>4)*4 + reg   [m89-verified]
__global__ __launch_bounds__(256) void attn_kernel(
    const float* __restrict__ obj, const unsigned short* __restrict__ wf,
    const float* __restrict__ hb, const float* __restrict__ watt,
    float* __restrict__ masks_out, float* __restrict__ attended)
{
  __shared__ float scores[256];
  __shared__ float red[8];
  __shared__ float attw[4][128];

  const int b = (int)blockIdx.x;
  const int tid = (int)threadIdx.x;
  const int w = tid >> 6, l = tid & 63;
  const int l15 = l & 15, lg = l >> 4;

  const float* objb = obj + (size_t)b * 32768;

  // ---- load this wave's 64 obj rows as A fragments (bf16, registers only)
  short8 afrag[4][4];
#pragma unroll
  for (int mt = 0; mt < 4; ++mt) {
    const int p = w * 64 + mt * 16 + l15;
#pragma unroll
    for (int kt = 0; kt < 4; ++kt) {
      union { short8 s8; unsigned u[4]; } fr;
#pragma unroll
      for (int half = 0; half < 2; ++half) {
        const int f = kt * 32 + half * 16 + lg * 4;
        const float4 v = *(const float4*)&objb[p * 128 + f];
        fr.u[half * 2 + 0] = (unsigned)f2bf(v.x) | ((unsigned)f2bf(v.y) << 16);
        fr.u[half * 2 + 1] = (unsigned)f2bf(v.z) | ((unsigned)f2bf(v.w) << 16);
      }
      afrag[mt][kt] = fr.s8;
    }
  }

  // ---- S = obj @ W_feat.T, fused tanh(S+hb) . W_att accumulation ----
  float ps[4][4] = {};
  const float* hbb = hb + (size_t)b * 512;
  for (int nc = 0; nc < 32; ++nc) {
    const int hh = nc * 16 + l15;
    const unsigned short* wrow = wf + hh * 128;
    union { short8 s8; unsigned u[4]; } bfr[4];
#pragma unroll
    for (int kt = 0; kt < 4; ++kt) {
      const uint2 lo = *(const uint2*)&wrow[kt * 32 + lg * 4];
      const uint2 hi = *(const uint2*)&wrow[kt * 32 + 16 + lg * 4];
      bfr[kt].u[0] = lo.x; bfr[kt].u[1] = lo.y; bfr[kt].u[2] = hi.x; bfr[kt].u[3] = hi.y;
    }
    const float hbv = hbb[hh];
    const float wav = watt[hh];
#pragma unroll
    for (int mt = 0; mt < 4; ++mt) {
      f32x4 acc = {0.f, 0.f, 0.f, 0.f};
#pragma unroll
      for (int kt = 0; kt < 4; ++kt)
        acc = __builtin_amdgcn_mfma_f32_16x16x32_bf16(afrag[mt][kt], bfr[kt].s8, acc, 0, 0, 0);
#pragma unroll
      for (int r = 0; r < 4; ++r)
        ps[mt][r] += wav * fast_tanh(acc[r] + hbv);
    }
  }

  // ---- reduce partial scores over the 16 col-lanes -> scores[p] ----
#pragma unroll
  for (int mt = 0; mt < 4; ++mt)
#pragma unroll
    for (int r = 0; r < 4; ++r) {
      float v = ps[mt][r];
      v += __shfl_xor(v, 1);
      v += __shfl_xor(v, 2);
      v += __shfl_xor(v, 4);
      v += __shfl_xor(v, 8);
      if (l15 == 0) scores[w * 64 + mt * 16 + lg * 4 + r] = v;
    }
  __syncthreads();

  // ---- softmax over 256 scores (thread t owns p=t) ----
  const float s = scores[tid];
  float mx = s;
#pragma unroll
  for (int off = 32; off > 0; off >>= 1) mx = fmaxf(mx, __shfl_xor(mx, off));
  if (l == 0) red[w] = mx;
  __syncthreads();
  mx = fmaxf(fmaxf(red[0], red[1]), fmaxf(red[2], red[3]));
  const float e = __expf(s - mx);
  float sm = e;
#pragma unroll
  for (int off = 32; off > 0; off >>= 1) sm += __shfl_xor(sm, off);
  if (l == 0) red[4 + w] = sm;
  __syncthreads();
  const float tot = red[4] + red[5] + red[6] + red[7];
  const float mymask = e / tot;
  masks_out[(size_t)b * 256 + tid] = mymask;

  // ---- attended = sum_p mask[p] * obj[p][f], from register fragments ----
  float att_acc[8][4] = {};
#pragma unroll
  for (int mt = 0; mt < 4; ++mt) {
    const float mk = __shfl(mymask, mt * 16 + l15);   // mask for p = w*64+mt*16+l15
#pragma unroll
    for (int kt = 0; kt < 4; ++kt)
#pragma unroll
      for (int half = 0; half < 2; ++half)
#pragma unroll
        for (int j = 0; j < 4; ++j)
          att_acc[kt * 2 + half][j] += mk * bf2f((unsigned short)afrag[mt][kt][half * 4 + j]);
  }
#pragma unroll
  for (int slot = 0; slot < 8; ++slot)
#pragma unroll
    for (int j = 0; j < 4; ++j) {
      float v = att_acc[slot][j];
      v += __shfl_xor(v, 1);
      v += __shfl_xor(v, 2);
      v += __shfl_xor(v, 4);
      v += __shfl_xor(v, 8);
      if (l15 == 0) {
        const int kt = slot >> 1, half = slot & 1;
        attw[w][kt * 32 + half * 16 + lg * 4 + j] = v;
      }
    }
  __syncthreads();
  if (tid < 128)
    attended[(size_t)b * 128 + tid] =
        attw[0][tid] + attw[1][tid] + attw[2][tid] + attw[3][tid];
}

// ---------------------------------------------------------------------------
extern "C" void kernel_launch(void* const* d_in, const int* in_sizes, int n_in,
                              void* d_out, int out_size, void* d_ws, size_t ws_size,
                              hipStream_t stream) {
  (void)in_sizes; (void)n_in; (void)out_size; (void)ws_size;
  const float* step   = (const float*)d_in[0];
  const float* tf     = (const float*)d_in[1];
  const float* obj    = (const float*)d_in[2];
  const float* h1prev = (const float*)d_in[3];
  const float* h2prev = (const float*)d_in[4];
  const float* W_td1  = (const float*)d_in[5];
  const float* W_td2  = (const float*)d_in[6];
  const float* W_td3  = (const float*)d_in[7];
  const float* W_td   = (const float*)d_in[8];
  const float* W_feat = (const float*)d_in[9];
  const float* W_hidd = (const float*)d_in[10];
  const float* W_att  = (const float*)d_in[11];
  const float* W_l1   = (const float*)d_in[12];
  const float* W_l2   = (const float*)d_in[13];
  const float* W_l    = (const float*)d_in[14];
  const float* g1Wih  = (const float*)d_in[15];
  const float* g1Whh  = (const float*)d_in[16];
  const float* g1bih  = (const float*)d_in[17];
  const float* g1bhh  = (const float*)d_in[18];
  const float* g2Wih  = (const float*)d_in[19];
  const float* g2Whh  = (const float*)d_in[20];
  const float* g2bih  = (const float*)d_in[21];
  const float* g2bhh  = (const float*)d_in[22];

  float* h1    = (float*)d_out;             // 1024*512
  float* h2    = (float*)d_out + 524288;    // 1024*512
  float* masks = (float*)d_out + 1048576;   // 1024*256

  float* ws   = (float*)d_ws;
  float* td    = ws;                 // 131072
  float* td2   = ws + 131072;        // 131072
  float* gi    = ws + 262144;        // 1572864 (shared GRU1/GRU2)
  float* gh    = ws + 1835008;       // 1572864
  float* hbuf  = ws + 3407872;       // 524288
  float* att   = ws + 3932160;       // 131072
  float* lang  = ws + 4063232;       // 131072
  float* lang2 = ws + 4194304;       // 131072
  unsigned short* wfb = (unsigned short*)(ws + 4325376);  // 65536 bf16

  const dim3 blk(256);

  // W_feat -> bf16 (independent)
  cvt_bf16<<<dim3(256), blk, 0, stream>>>(W_feat, wfb, 65536);

  // td chain
  gemm_nt<<<dim3(16, 2), blk, 0, stream>>>(step,   W_td3, nullptr, td,  1024, 128, 300, 0);
  gemm_nt<<<dim3(16, 2), blk, 0, stream>>>(h2prev, W_td1, nullptr, td,  1024, 128, 512, 1);
  gemm_nt<<<dim3(16, 2), blk, 0, stream>>>(tf,     W_td2, nullptr, td,  1024, 128, 128, 1 | (2 << 2)); // +tanh
  gemm_nt<<<dim3(16, 2), blk, 0, stream>>>(td,     W_td,  nullptr, td2, 1024, 128, 128, (1 << 2));     // relu

  // GRU1
  gemm_nt<<<dim3(16, 24), blk, 0, stream>>>(td2,    g1Wih, g1bih, gi, 1024, 1536, 128, 0);
  gemm_nt<<<dim3(16, 24), blk, 0, stream>>>(h1prev, g1Whh, g1bhh, gh, 1024, 1536, 512, 0);
  gru_combine<<<dim3(2048), blk, 0, stream>>>(gi, gh, h1prev, h1);

  // hb = h1 @ W_hidd.T
  gemm_nt<<<dim3(16, 8), blk, 0, stream>>>(h1, W_hidd, nullptr, hbuf, 1024, 512, 512, 0);

  // attention (writes masks to d_out, attended to ws)
  attn_kernel<<<dim3(1024), blk, 0, stream>>>(obj, wfb, hbuf, W_att, masks, att);

  // lang fusion
  gemm_nt<<<dim3(16, 2), blk, 0, stream>>>(att,  W_l1, nullptr, lang,  1024, 128, 128, 0);
  gemm_nt<<<dim3(16, 2), blk, 0, stream>>>(h1,   W_l2, nullptr, lang,  1024, 128, 512, 1 | (2 << 2)); // +tanh
  gemm_nt<<<dim3(16, 2), blk, 0, stream>>>(lang, W_l,  nullptr, lang2, 1024, 128, 128, (1 << 2));     // relu

  // GRU2
  gemm_nt<<<dim3(16, 24), blk, 0, stream>>>(lang2,  g2Wih, g2bih, gi, 1024, 1536, 128, 0);
  gemm_nt<<<dim3(16, 24), blk, 0, stream>>>(h2prev, g2Whh, g2bhh, gh, 1024, 1536, 512, 0);
  gru_combine<<<dim3(2048), blk, 0, stream>>>(gi, gh, h2prev, h2);
}

// Round 4
// 496.732 us; speedup vs baseline: 1.4039x; 1.4039x over previous
//
#include <hip/hip_runtime.h>
#include <hip/hip_bf16.h>
#include <stdint.h>

// ---------------------------------------------------------------------------
// TDBU caption step, bf16-MFMA everywhere.
//   cvt_all: batch fp32->bf16 (K zero-padded to /32) for inputs+weights
//   gemm_bf16: C = A(M,K)@W(N,K)^T [+bias][+acc][relu/tanh] -> fp32 C and/or bf16 Cb
//   td chain (3 acc gemms + 1), GRU1 (2 gemms + combine), hb gemm,
//   attn (fused MFMA + softmax + weighted sum), lang chain, GRU2.
// ---------------------------------------------------------------------------

typedef __attribute__((ext_vector_type(8))) short short8;
typedef __attribute__((ext_vector_type(4))) float f32x4;

#define DEV static __device__ __forceinline__

DEV float rcp_f(float x) { return __builtin_amdgcn_rcpf(x); }
DEV float fast_tanh(float x) {
  float ax = fabsf(x);
  float e = __expf(2.0f * ax);              // inf for big ax -> t=1
  float t = 1.0f - 2.0f * rcp_f(e + 1.0f);
  return x < 0.0f ? -t : t;
}
DEV float fast_sigmoid(float x) { return rcp_f(1.0f + __expf(-x)); }
DEV unsigned short f2bf(float x) {
  unsigned u = __float_as_uint(x);
  u += 0x7fffu + ((u >> 16) & 1u);
  return (unsigned short)(u >> 16);
}
DEV float bf2f(unsigned short s) { return __uint_as_float(((unsigned)s) << 16); }

// ---------------- batched fp32 -> bf16 with K padding -----------------------
#define NJOBS 17
struct CvtJobs {
  const float* src[NJOBS];
  unsigned short* dst[NJOBS];
};
// job order: step, tf, h1p, h2p, wtd3, wtd1, wtd2, wtd, wfeat, whidd,
//            wl1, wl2, wl, g1wih, g1whh, g2wih, g2whh
__global__ __launch_bounds__(256) void cvt_all(CvtJobs jobs) {
  const int cum[NJOBS + 1] = {0, 327680, 458752, 983040, 1507328, 1548288,
                              1613824, 1630208, 1646592, 1712128, 1974272,
                              1990656, 2056192, 2072576, 2269184, 3055616,
                              3252224, 4038656};
  const int Ks[NJOBS]  = {300, 128, 512, 512, 300, 512, 128, 128, 128, 512,
                          128, 512, 128, 128, 512, 128, 512};
  const int Kps[NJOBS] = {320, 128, 512, 512, 320, 512, 128, 128, 128, 512,
                          128, 512, 128, 128, 512, 128, 512};
  int g = blockIdx.x * 256 + (int)threadIdx.x;
  if (g >= 4038656) return;
  int j = 0;
  while (g >= cum[j + 1]) ++j;
  const int local = g - cum[j];
  const int Kp = Kps[j], K = Ks[j];
  const int r = local / Kp, c = local - r * Kp;
  jobs.dst[j][local] = (c < K) ? f2bf(jobs.src[j][(size_t)r * K + c])
                               : (unsigned short)0;
}

// ---------------- bf16 MFMA GEMM: C = A(M,K) @ W(N,K)^T --------------------
// A,W bf16 row-major, strides lda/ldw (multiples of 32, 16B-aligned rows).
// M,N multiples of 64. flags: bit0 acc (C += , requires C); act=(flags>>2):
// 0 none, 1 relu, 2 tanh. C fp32 (nullable), Cb bf16 (nullable), bias fp32.
#define FACC 1
#define FRELU (1 << 2)
#define FTANH (2 << 2)
__global__ __launch_bounds__(256) void gemm_bf16(
    const unsigned short* __restrict__ A, const unsigned short* __restrict__ W,
    const float* __restrict__ bias, float* __restrict__ C,
    unsigned short* __restrict__ Cb, int M, int N, int K,
    int lda, int ldw, int flags)
{
  __shared__ unsigned short As[64][40];   // +8 pad: 80B rows, 16B aligned
  __shared__ unsigned short Ws[64][40];
  const int bm = blockIdx.x * 64, bn = blockIdx.y * 64;
  const int tid = (int)threadIdx.x;
  const int w = tid >> 6, l = tid & 63, l15 = l & 15, lg = l >> 4;
  const int wr = w >> 1, wc = w & 1;
  const int srow = tid >> 2, sq = tid & 3;

  f32x4 acc[2][2] = {};

  for (int k0 = 0; k0 < K; k0 += 32) {
    const uint4 va = *(const uint4*)(A + (size_t)(bm + srow) * lda + k0 + sq * 8);
    const uint4 vw = *(const uint4*)(W + (size_t)(bn + srow) * ldw + k0 + sq * 8);
    __syncthreads();
    *(uint4*)&As[srow][sq * 8] = va;
    *(uint4*)&Ws[srow][sq * 8] = vw;
    __syncthreads();

    short8 af[2], bf[2];
#pragma unroll
    for (int mi = 0; mi < 2; ++mi) {
      const int ar = wr * 32 + mi * 16 + l15;
      union { short8 s8; uint2 u[2]; } f;
      f.u[0] = *(const uint2*)&As[ar][lg * 4];
      f.u[1] = *(const uint2*)&As[ar][16 + lg * 4];
      af[mi] = f.s8;
    }
#pragma unroll
    for (int ni = 0; ni < 2; ++ni) {
      const int br = wc * 32 + ni * 16 + l15;
      union { short8 s8; uint2 u[2]; } f;
      f.u[0] = *(const uint2*)&Ws[br][lg * 4];
      f.u[1] = *(const uint2*)&Ws[br][16 + lg * 4];
      bf[ni] = f.s8;
    }
#pragma unroll
    for (int mi = 0; mi < 2; ++mi)
#pragma unroll
      for (int ni = 0; ni < 2; ++ni)
        acc[mi][ni] = __builtin_amdgcn_mfma_f32_16x16x32_bf16(
            af[mi], bf[ni], acc[mi][ni], 0, 0, 0);
  }

  const int act = flags >> 2;
#pragma unroll
  for (int mi = 0; mi < 2; ++mi)
#pragma unroll
    for (int ni = 0; ni < 2; ++ni)
#pragma unroll
      for (int r = 0; r < 4; ++r) {
        const int m = bm + wr * 32 + mi * 16 + lg * 4 + r;
        const int n = bn + wc * 32 + ni * 16 + l15;
        float v = acc[mi][ni][r];
        if (bias) v += bias[n];
        if (flags & FACC) v += C[(size_t)m * N + n];
        if (act == 1) v = fmaxf(v, 0.0f);
        else if (act == 2) v = fast_tanh(v);
        if (C) C[(size_t)m * N + n] = v;
        if (Cb) Cb[(size_t)m * N + n] = f2bf(v);
      }
}

// ---------------- GRU combine (bf16 gates, fp32 h) --------------------------
__global__ __launch_bounds__(256) void gru_combine(
    const unsigned short* __restrict__ gi, const unsigned short* __restrict__ gh,
    const float* __restrict__ hprev, float* __restrict__ hnew,
    unsigned short* __restrict__ hnewb)
{
  const int i4 = blockIdx.x * 256 + (int)threadIdx.x;   // over 131072
  const int b = i4 >> 7, j4 = (i4 & 127) * 4;
  const unsigned short* gib = gi + (size_t)b * 1536 + j4;
  const unsigned short* ghb = gh + (size_t)b * 1536 + j4;
  union { uint2 u; unsigned short s[4]; } gr, gz, gn, hr, hz, hn;
  gr.u = *(const uint2*)(gib);        hr.u = *(const uint2*)(ghb);
  gz.u = *(const uint2*)(gib + 512);  hz.u = *(const uint2*)(ghb + 512);
  gn.u = *(const uint2*)(gib + 1024); hn.u = *(const uint2*)(ghb + 1024);
  const float4 hp = *(const float4*)&hprev[(size_t)b * 512 + j4];
  const float hpv[4] = {hp.x, hp.y, hp.z, hp.w};
  float o[4];
  union { uint2 u; unsigned short s[4]; } ob;
#pragma unroll
  for (int k = 0; k < 4; ++k) {
    const float r = fast_sigmoid(bf2f(gr.s[k]) + bf2f(hr.s[k]));
    const float z = fast_sigmoid(bf2f(gz.s[k]) + bf2f(hz.s[k]));
    const float n = fast_tanh(bf2f(gn.s[k]) + r * bf2f(hn.s[k]));
    o[k] = (1.0f - z) * n + z * hpv[k];
    ob.s[k] = f2bf(o[k]);
  }
  float4 ov; ov.x = o[0]; ov.y = o[1]; ov.z = o[2]; ov.w = o[3];
  *(float4*)&hnew[(size_t)b * 512 + j4] = ov;
  if (hnewb) *(uint2*)&hnewb[(size_t)b * 512 + j4] = ob.u;
}

// ---------------- fused attention ------------------------------------------
__global__ __launch_bounds__(256) void attn_kernel(
    const float* __restrict__ obj, const unsigned short* __restrict__ wf,
    const float* __restrict__ hb, const float* __restrict__ watt,
    float* __restrict__ masks_out, unsigned short* __restrict__ attb)
{
  __shared__ float scores[256];
  __shared__ float red[8];
  __shared__ float attw[4][128];
  __shared__ float hbs[512];
  __shared__ float wats[512];

  const int b = (int)blockIdx.x;
  const int tid = (int)threadIdx.x;
  const int w = tid >> 6, l = tid & 63;
  const int l15 = l & 15, lg = l >> 4;

  const float* objb = obj + (size_t)b * 32768;
  const float* hbb = hb + (size_t)b * 512;

  for (int i = tid; i < 512; i += 256) { hbs[i] = hbb[i]; wats[i] = watt[i]; }

  // this wave's 64 obj rows as bf16 A fragments (registers)
  short8 afrag[4][4];
#pragma unroll
  for (int mt = 0; mt < 4; ++mt) {
    const int p = w * 64 + mt * 16 + l15;
#pragma unroll
    for (int kt = 0; kt < 4; ++kt) {
      union { short8 s8; unsigned u[4]; } fr;
#pragma unroll
      for (int half = 0; half < 2; ++half) {
        const int f = kt * 32 + half * 16 + lg * 4;
        const float4 v = *(const float4*)&objb[p * 128 + f];
        fr.u[half * 2 + 0] = (unsigned)f2bf(v.x) | ((unsigned)f2bf(v.y) << 16);
        fr.u[half * 2 + 1] = (unsigned)f2bf(v.z) | ((unsigned)f2bf(v.w) << 16);
      }
      afrag[mt][kt] = fr.s8;
    }
  }
  __syncthreads();

  // scores: S = obj@W_feat.T fused with sum_h watt*tanh(S+hb)
  float ps[4][4] = {};
  unsigned cur[4][4], nxt[4][4];
  {
    const unsigned short* wrow = wf + (size_t)l15 * 128;
#pragma unroll
    for (int kt = 0; kt < 4; ++kt) {
      const uint2 lo = *(const uint2*)&wrow[kt * 32 + lg * 4];
      const uint2 hi = *(const uint2*)&wrow[kt * 32 + 16 + lg * 4];
      cur[kt][0] = lo.x; cur[kt][1] = lo.y; cur[kt][2] = hi.x; cur[kt][3] = hi.y;
    }
  }
  for (int nc = 0; nc < 32; ++nc) {
    if (nc < 31) {
      const unsigned short* wrow = wf + (size_t)((nc + 1) * 16 + l15) * 128;
#pragma unroll
      for (int kt = 0; kt < 4; ++kt) {
        const uint2 lo = *(const uint2*)&wrow[kt * 32 + lg * 4];
        const uint2 hi = *(const uint2*)&wrow[kt * 32 + 16 + lg * 4];
        nxt[kt][0] = lo.x; nxt[kt][1] = lo.y; nxt[kt][2] = hi.x; nxt[kt][3] = hi.y;
      }
    }
    const int hh = nc * 16 + l15;
    const float hbv = hbs[hh];
    const float wav = wats[hh];
#pragma unroll
    for (int mt = 0; mt < 4; ++mt) {
      f32x4 acc = {0.f, 0.f, 0.f, 0.f};
#pragma unroll
      for (int kt = 0; kt < 4; ++kt) {
        union { short8 s8; unsigned u[4]; } f;
        f.u[0] = cur[kt][0]; f.u[1] = cur[kt][1];
        f.u[2] = cur[kt][2]; f.u[3] = cur[kt][3];
        acc = __builtin_amdgcn_mfma_f32_16x16x32_bf16(afrag[mt][kt], f.s8, acc, 0, 0, 0);
      }
#pragma unroll
      for (int r = 0; r < 4; ++r)
        ps[mt][r] += wav * fast_tanh(acc[r] + hbv);
    }
#pragma unroll
    for (int kt = 0; kt < 4; ++kt)
#pragma unroll
      for (int q = 0; q < 4; ++q) cur[kt][q] = nxt[kt][q];
  }

#pragma unroll
  for (int mt = 0; mt < 4; ++mt)
#pragma unroll
    for (int r = 0; r < 4; ++r) {
      float v = ps[mt][r];
      v += __shfl_xor(v, 1);
      v += __shfl_xor(v, 2);
      v += __shfl_xor(v, 4);
      v += __shfl_xor(v, 8);
      if (l15 == 0) scores[w * 64 + mt * 16 + lg * 4 + r] = v;
    }
  __syncthreads();

  // softmax over 256 (thread t owns p=t)
  const float s = scores[tid];
  float mx = s;
#pragma unroll
  for (int off = 32; off > 0; off >>= 1) mx = fmaxf(mx, __shfl_xor(mx, off));
  if (l == 0) red[w] = mx;
  __syncthreads();
  mx = fmaxf(fmaxf(red[0], red[1]), fmaxf(red[2], red[3]));
  const float e = __expf(s - mx);
  float sm = e;
#pragma unroll
  for (int off = 32; off > 0; off >>= 1) sm += __shfl_xor(sm, off);
  if (l == 0) red[4 + w] = sm;
  __syncthreads();
  const float mymask = e * rcp_f(red[4] + red[5] + red[6] + red[7]);
  masks_out[(size_t)b * 256 + tid] = mymask;

  // attended = sum_p mask[p]*obj[p][:], from register fragments
  float att_acc[8][4] = {};
#pragma unroll
  for (int mt = 0; mt < 4; ++mt) {
    const float mk = __shfl(mymask, mt * 16 + l15);
#pragma unroll
    for (int kt = 0; kt < 4; ++kt)
#pragma unroll
      for (int half = 0; half < 2; ++half)
#pragma unroll
        for (int j = 0; j < 4; ++j)
          att_acc[kt * 2 + half][j] += mk * bf2f((unsigned short)afrag[mt][kt][half * 4 + j]);
  }
#pragma unroll
  for (int slot = 0; slot < 8; ++slot)
#pragma unroll
    for (int j = 0; j < 4; ++j) {
      float v = att_acc[slot][j];
      v += __shfl_xor(v, 1);
      v += __shfl_xor(v, 2);
      v += __shfl_xor(v, 4);
      v += __shfl_xor(v, 8);
      if (l15 == 0) {
        const int kt = slot >> 1, half = slot & 1;
        attw[w][kt * 32 + half * 16 + lg * 4 + j] = v;
      }
    }
  __syncthreads();
  if (tid < 128)
    attb[(size_t)b * 128 + tid] =
        f2bf(attw[0][tid] + attw[1][tid] + attw[2][tid] + attw[3][tid]);
}

// ---------------------------------------------------------------------------
extern "C" void kernel_launch(void* const* d_in, const int* in_sizes, int n_in,
                              void* d_out, int out_size, void* d_ws, size_t ws_size,
                              hipStream_t stream) {
  (void)in_sizes; (void)n_in; (void)out_size; (void)ws_size;
  const float* step   = (const float*)d_in[0];
  const float* tf     = (const float*)d_in[1];
  const float* obj    = (const float*)d_in[2];
  const float* h1prev = (const float*)d_in[3];
  const float* h2prev = (const float*)d_in[4];
  const float* W_td1  = (const float*)d_in[5];
  const float* W_td2  = (const float*)d_in[6];
  const float* W_td3  = (const float*)d_in[7];
  const float* W_td   = (const float*)d_in[8];
  const float* W_feat = (const float*)d_in[9];
  const float* W_hidd = (const float*)d_in[10];
  const float* W_att  = (const float*)d_in[11];
  const float* W_l1   = (const float*)d_in[12];
  const float* W_l2   = (const float*)d_in[13];
  const float* W_l    = (const float*)d_in[14];
  const float* g1Wih  = (const float*)d_in[15];
  const float* g1Whh  = (const float*)d_in[16];
  const float* g1bih  = (const float*)d_in[17];
  const float* g1bhh  = (const float*)d_in[18];
  const float* g2Wih  = (const float*)d_in[19];
  const float* g2Whh  = (const float*)d_in[20];
  const float* g2bih  = (const float*)d_in[21];
  const float* g2bhh  = (const float*)d_in[22];

  float* h1    = (float*)d_out;
  float* h2    = (float*)d_out + 524288;
  float* masks = (float*)d_out + 1048576;

  // ---- workspace layout (bf16 elements unless noted) ----
  unsigned short* wsb = (unsigned short*)d_ws;
  unsigned short* step_b  = wsb + 0;        // 327680  (1024x320)
  unsigned short* tf_b    = wsb + 327680;   // 131072  (1024x128)
  unsigned short* h1p_b   = wsb + 458752;   // 524288  (1024x512)
  unsigned short* h2p_b   = wsb + 983040;   // 524288
  unsigned short* wtd3b   = wsb + 1507328;  // 40960   (128x320)
  unsigned short* wtd1b   = wsb + 1548288;  // 65536   (128x512)
  unsigned short* wtd2b   = wsb + 1613824;  // 16384
  unsigned short* wtdb    = wsb + 1630208;  // 16384
  unsigned short* wfeatb  = wsb + 1646592;  // 65536   (512x128)
  unsigned short* whiddb  = wsb + 1712128;  // 262144  (512x512)
  unsigned short* wl1b    = wsb + 1974272;  // 16384
  unsigned short* wl2b    = wsb + 1990656;  // 65536
  unsigned short* wlb     = wsb + 2056192;  // 16384
  unsigned short* g1wihb  = wsb + 2072576;  // 196608  (1536x128)
  unsigned short* g1whhb  = wsb + 2269184;  // 786432  (1536x512)
  unsigned short* g2wihb  = wsb + 3055616;  // 196608
  unsigned short* g2whhb  = wsb + 3252224;  // 786432
  unsigned short* h1b     = wsb + 4038656;  // 524288
  unsigned short* tdb     = wsb + 4562944;  // 131072
  unsigned short* td2b    = wsb + 4694016;  // 131072
  unsigned short* attb    = wsb + 4825088;  // 131072
  unsigned short* langb   = wsb + 4956160;  // 131072
  unsigned short* lang2b  = wsb + 5087232;  // 131072
  unsigned short* gi_b    = wsb + 5218304;  // 1572864 (1024x1536)
  unsigned short* gh_b    = wsb + 6791168;  // 1572864
  // fp32 scratch ALIASED onto gh_b region (lifetimes disjoint; see phases)
  float* scratchf = (float*)(wsb + 6791168);  // up to 1024x512 fp32

  const dim3 blk(256);

  // phase 0: all conversions
  CvtJobs jobs;
  const float* srcs[NJOBS] = {step, tf, h1prev, h2prev, W_td3, W_td1, W_td2,
                              W_td, W_feat, W_hidd, W_l1, W_l2, W_l,
                              g1Wih, g1Whh, g2Wih, g2Whh};
  unsigned short* dsts[NJOBS] = {step_b, tf_b, h1p_b, h2p_b, wtd3b, wtd1b,
                                 wtd2b, wtdb, wfeatb, whiddb, wl1b, wl2b, wlb,
                                 g1wihb, g1whhb, g2wihb, g2whhb};
  for (int i = 0; i < NJOBS; ++i) { jobs.src[i] = srcs[i]; jobs.dst[i] = dsts[i]; }
  cvt_all<<<dim3(15776), blk, 0, stream>>>(jobs);

  // phase 1: td chain (C accum in scratchf, fp32)
  gemm_bf16<<<dim3(16, 2), blk, 0, stream>>>(step_b, wtd3b, nullptr, scratchf, nullptr, 1024, 128, 320, 320, 320, 0);
  gemm_bf16<<<dim3(16, 2), blk, 0, stream>>>(h2p_b,  wtd1b, nullptr, scratchf, nullptr, 1024, 128, 512, 512, 512, FACC);
  gemm_bf16<<<dim3(16, 2), blk, 0, stream>>>(tf_b,   wtd2b, nullptr, scratchf, tdb,     1024, 128, 128, 128, 128, FACC | FTANH);
  gemm_bf16<<<dim3(16, 2), blk, 0, stream>>>(tdb,    wtdb,  nullptr, nullptr,  td2b,    1024, 128, 128, 128, 128, FRELU);

  // phase 2: GRU1
  gemm_bf16<<<dim3(16, 24), blk, 0, stream>>>(td2b,  g1wihb, g1bih, nullptr, gi_b, 1024, 1536, 128, 128, 128, 0);
  gemm_bf16<<<dim3(16, 24), blk, 0, stream>>>(h1p_b, g1whhb, g1bhh, nullptr, gh_b, 1024, 1536, 512, 512, 512, 0);
  gru_combine<<<dim3(512), blk, 0, stream>>>(gi_b, gh_b, h1prev, h1, h1b);

  // phase 3: hb = h1 @ W_hidd.T (fp32 out; overwrites dead gh_b region)
  gemm_bf16<<<dim3(16, 8), blk, 0, stream>>>(h1b, whiddb, nullptr, scratchf, nullptr, 1024, 512, 512, 512, 512, 0);

  // phase 4: attention
  attn_kernel<<<dim3(1024), blk, 0, stream>>>(obj, wfeatb, scratchf, W_att, masks, attb);

  // phase 5: lang chain
  gemm_bf16<<<dim3(16, 2), blk, 0, stream>>>(attb,  wl1b, nullptr, scratchf, nullptr, 1024, 128, 128, 128, 128, 0);
  gemm_bf16<<<dim3(16, 2), blk, 0, stream>>>(h1b,   wl2b, nullptr, scratchf, langb,   1024, 128, 512, 512, 512, FACC | FTANH);
  gemm_bf16<<<dim3(16, 2), blk, 0, stream>>>(langb, wlb,  nullptr, nullptr,  lang2b,  1024, 128, 128, 128, 128, FRELU);

  // phase 6: GRU2 (gh_b reused; scratchf dead)
  gemm_bf16<<<dim3(16, 24), blk, 0, stream>>>(lang2b, g2wihb, g2bih, nullptr, gi_b, 1024, 1536, 128, 128, 128, 0);
  gemm_bf16<<<dim3(16, 24), blk, 0, stream>>>(h2p_b,  g2whhb, g2bhh, nullptr, gh_b, 1024, 1536, 512, 512, 512, 0);
  gru_combine<<<dim3(512), blk, 0, stream>>>(gi_b, gh_b, h2prev, h2, nullptr);
}